// Round 2
// baseline (295.138 us; speedup 1.0000x reference)
//
#include <hip/hip_runtime.h>
#include <math.h>

#define T_STEPS  512
#define N_ENVS   256
#define STATE    64
#define HID      128
#define NTHREADS 512   // 8 waves
#define XPAD     72    // xh row stride in f16 (64 + 8 pad: breaks 16-way bank conflict)

typedef _Float16 half8   __attribute__((ext_vector_type(8)));
typedef _Float16 half4_t __attribute__((ext_vector_type(4)));
typedef float    floatx4 __attribute__((ext_vector_type(4)));

// Raw workgroup barrier: LDS visibility only (lgkmcnt), NO vmcnt/expcnt drain.
// lgkmcnt(0) also guarantees this wave's ds_reads completed before it signals
// the barrier, so the next step's buf writes cannot clobber in-flight reads.
#define BAR() asm volatile("s_waitcnt lgkmcnt(0)\n\ts_barrier" ::: "memory")

// v_exp_f32 is natively 2^x. Weights are pre-scaled into the exp2 domain.
__device__ __forceinline__ float fexp2(float v) {
    float r;
    asm("v_exp_f32 %0, %1" : "=v"(r) : "v"(v));
    return r;
}
// 2^(-|v|) with free source modifiers (R7 paid a VALU op for -fabsf).
__device__ __forceinline__ float fexp2_nabs(float v) {
    float r;
    asm("v_exp_f32 %0, -|%1|" : "=v"(r) : "v"(v));
    return r;
}
// cross-lane pull: dst = src[addr>>2] (addr in bytes)
__device__ __forceinline__ float bpermf(int addr, float v) {
    return __int_as_float(__builtin_amdgcn_ds_bpermute(addr, __float_as_int(v)));
}

// One block per env, 8 waves. Wave w owns gate rows j=16w+c for r (row j),
// z (row 128+j), n (row 256+j); lane c owns hidden unit j, quads redundant.
//
// R8 (spine shrink):
//  - gx distribution via in-wave ds_bpermute into 48 registers at chunk start:
//    no gxp LDS array, no per-step gxp ds_read, one barrier per chunk removed
//    (x-GEMM producer lane (s>>2,c) == consumer's source lane, same wave)
//  - r-gate gx term and scaled bhn folded into MFMA C-in (adds off the spine)
//  - e_t via v_exp_f32 -|x| source modifier (no explicit neg/abs VALU op)
//  - hr updated only at s==15
__global__ __launch_bounds__(NTHREADS, 2) void gru_r8(
    const float* __restrict__ x,      // (T*N, STATE)
    const float* __restrict__ h0,     // (N, HID)
    const float* __restrict__ masks,  // (T*N, 1) in {0,1}
    const float* __restrict__ wih,    // (3H, STATE)
    const float* __restrict__ whh,    // (3H, HID)
    const float* __restrict__ bih,    // (3H)
    const float* __restrict__ bhh,    // (3H)
    float* __restrict__ out)          // ys (T*N,H) then h_final (N,H)
{
    const int b    = blockIdx.x;
    const int tid  = threadIdx.x;
    const int w    = tid >> 6;
    const int lane = tid & 63;
    const int c    = lane & 15;
    const int quad = lane >> 4;
    const int j    = 16 * w + c;            // owned hidden unit (0..127)

    __shared__ __align__(16) _Float16 buf[2][HID];        // masked h f16, step parity
    __shared__ __align__(16) _Float16 xh[2][16][XPAD];    // x f16 per chunk (padded rows)

    const float SRZ = -1.44269504088896341f;   // -log2(e)
    const float SN  = -2.88539008177792681f;   // -2*log2(e)
    const float scl[3] = { SRZ, SRZ, SN };

    // ---- persistent W_hh B-fragments (K=128 -> 4 chunks), exp2-pre-scaled ----
    const int rowb[3] = { j, HID + j, 2 * HID + j };
    half8 Bh[3][4];
#pragma unroll
    for (int ti = 0; ti < 3; ++ti) {
        const int g = rowb[ti];
        const float sc = scl[ti];
#pragma unroll
        for (int kt = 0; kt < 4; ++kt) {
            const float* src = whh + (size_t)g * HID + kt * 32 + quad * 8;
            const float4 p0 = *(const float4*)(src);
            const float4 p1 = *(const float4*)(src + 4);
            half8 hb;
            hb[0] = (_Float16)(sc * p0.x); hb[1] = (_Float16)(sc * p0.y);
            hb[2] = (_Float16)(sc * p0.z); hb[3] = (_Float16)(sc * p0.w);
            hb[4] = (_Float16)(sc * p1.x); hb[5] = (_Float16)(sc * p1.y);
            hb[6] = (_Float16)(sc * p1.z); hb[7] = (_Float16)(sc * p1.w);
            Bh[ti][kt] = hb;
        }
    }
    // ---- persistent W_ih B-fragments (K=64 -> 2 chunks), exp2-pre-scaled ----
    half8 Bx[3][2];
#pragma unroll
    for (int ti = 0; ti < 3; ++ti) {
        const int g = rowb[ti];
        const float sc = scl[ti];
#pragma unroll
        for (int kt = 0; kt < 2; ++kt) {
            const float* src = wih + (size_t)g * STATE + kt * 32 + quad * 8;
            const float4 p0 = *(const float4*)(src);
            const float4 p1 = *(const float4*)(src + 4);
            half8 hb;
            hb[0] = (_Float16)(sc * p0.x); hb[1] = (_Float16)(sc * p0.y);
            hb[2] = (_Float16)(sc * p0.z); hb[3] = (_Float16)(sc * p0.w);
            hb[4] = (_Float16)(sc * p1.x); hb[5] = (_Float16)(sc * p1.y);
            hb[6] = (_Float16)(sc * p1.z); hb[7] = (_Float16)(sc * p1.w);
            Bx[ti][kt] = hb;
        }
    }

    // scaled biases (exp2 domain)
    const float br  = SRZ * (bih[j] + bhh[j]);
    const float bz  = SRZ * (bih[HID + j] + bhh[HID + j]);
    const float bxn = SN  * bih[2 * HID + j];
    const float bhn = SN  * bhh[2 * HID + j];

    const floatx4 zero4 = {0.f, 0.f, 0.f, 0.f};
    floatx4 cbhn = zero4; cbhn[0] = bhn;   // loop-invariant C-in for n b-chain
    floatx4 crin = zero4;                  // per-step C-in for r b-chain ([0] set per step)

    // bpermute byte addresses: source lane (q*16 + c) for quad-group q
    const int pa0 = (0 * 16 + c) * 4;
    const int pa1 = (1 * 16 + c) * 4;
    const int pa2 = (2 * 16 + c) * 4;
    const int pa3 = (3 * 16 + c) * 4;

    // ---- state / staging init ----
    float hr = h0[(size_t)b * HID + j];
    float hm = masks[b] * hr;
    if (quad == 0) buf[0][j] = (_Float16)hm;

    float4 xp = {0.f, 0.f, 0.f, 0.f};
    if (tid < 256) {   // xh[0] = x steps 0..15 ; xp = x steps 16..31
        const int k = tid >> 4, cc = (tid & 15) * 4;
        const float4 xv = *(const float4*)(x + ((size_t)k * N_ENVS + b) * STATE + cc);
        half4_t hx = {(_Float16)xv.x, (_Float16)xv.y, (_Float16)xv.z, (_Float16)xv.w};
        *(half4_t*)&xh[0][k][cc] = hx;
        xp = *(const float4*)(x + ((size_t)(16 + k) * N_ENVS + b) * STATE + cc);
    }
    // mask windows: lane l holds masks[tb+1+l] for current chunk (l = lane&15)
    float mwin     = masks[(size_t)(1  + (lane & 15)) * N_ENVS + b];
    float mwin_nxt = masks[(size_t)(17 + (lane & 15)) * N_ENVS + b];

    float o[4] = {0.f, 0.f, 0.f, 0.f};   // output regs: step s=quad*4+i -> o[i]

    BAR();   // xh[0] + buf[0] visible

    for (int tc = 0; tc < 32; ++tc) {
        // ======== chunk boundary (once per 16 steps, no extra barrier) ========
        if (tc > 0) {   // store previous chunk's outputs straight from registers
            const int tbp = (tc - 1) * 16;
#pragma unroll
            for (int i = 0; i < 4; ++i)
                out[((size_t)(tbp + quad * 4 + i) * N_ENVS + b) * HID + j] = o[i];
            // roll mask window
            mwin = mwin_nxt;
            const int stm = (tc + 1) * 16 + 1 + (lane & 15);
            mwin_nxt = masks[(size_t)(stm < T_STEPS ? stm : T_STEPS - 1) * N_ENVS + b];
        }
        if (tid < 256) {   // xp (steps (tc+1)*16..+15) -> xh for next chunk
            const int k = tid >> 4, cc = (tid & 15) * 4;
            half4_t hx = {(_Float16)xp.x, (_Float16)xp.y, (_Float16)xp.z, (_Float16)xp.w};
            *(half4_t*)&xh[(tc + 1) & 1][k][cc] = hx;
            const int st = (tc + 2) * 16 + k;
            if (st < T_STEPS)
                xp = *(const float4*)(x + ((size_t)st * N_ENVS + b) * STATE + cc);
        }

        // batched x-projection GEMM for this chunk: A row m=c is x[step tb+c][*]
        // D[step=quad*4+i][col=c]; distributed to all quads via in-wave bpermute.
        float gxr[16], gxz[16], gxn[16];   // statically indexed (loops fully unrolled)
        {
            const _Float16* xr = &xh[tc & 1][c][0];
            half8 ax0 = *(const half8*)&xr[quad * 8];
            half8 ax1 = *(const half8*)&xr[32 + quad * 8];
            floatx4 g0 = __builtin_amdgcn_mfma_f32_16x16x32_f16(ax0, Bx[0][0], zero4, 0, 0, 0);
            floatx4 g1 = __builtin_amdgcn_mfma_f32_16x16x32_f16(ax0, Bx[1][0], zero4, 0, 0, 0);
            floatx4 g2 = __builtin_amdgcn_mfma_f32_16x16x32_f16(ax0, Bx[2][0], zero4, 0, 0, 0);
            g0 = __builtin_amdgcn_mfma_f32_16x16x32_f16(ax1, Bx[0][1], g0, 0, 0, 0);
            g1 = __builtin_amdgcn_mfma_f32_16x16x32_f16(ax1, Bx[1][1], g1, 0, 0, 0);
            g2 = __builtin_amdgcn_mfma_f32_16x16x32_f16(ax1, Bx[2][1], g2, 0, 0, 0);
            // biases folded pre-shuffle (per-unit bias == per-col, same c at source)
#pragma unroll
            for (int i = 0; i < 4; ++i) {
                g0[i] += br;
                g1[i] += bz;
                g2[i] += bxn;
            }
#pragma unroll
            for (int s = 0; s < 16; ++s) {
                const int a = (s >> 2) == 0 ? pa0 : (s >> 2) == 1 ? pa1
                            : (s >> 2) == 2 ? pa2 : pa3;
                gxr[s] = bpermf(a, g0[s & 3]);
                gxz[s] = bpermf(a, g1[s & 3]);
                gxn[s] = bpermf(a, g2[s & 3]);
            }
        }

        // ======== 16 recurrence steps, one barrier each ========
#pragma unroll
        for (int s = 0; s < 16; ++s) {
            const _Float16* bufc = buf[s & 1];
            _Float16* bufn = (_Float16*)buf[(s + 1) & 1];

            // A fragments: broadcast masked h; first-layer operands (a0,a2) first
            half8 a0 = *(const half8*)(bufc + 0 * 32 + quad * 8);
            half8 a2 = *(const half8*)(bufc + 2 * 32 + quad * 8);
            half8 a1 = *(const half8*)(bufc + 1 * 32 + quad * 8);
            half8 a3 = *(const half8*)(bufc + 3 * 32 + quad * 8);
            // masks[t+1], wave-uniform (window register always in-bounds)
            const float mn = __int_as_float(__builtin_amdgcn_readlane(__float_as_int(mwin), s));

            crin[0] = gxr[s];   // r-gate x-term rides the MFMA accumulator

            // 12 MFMAs, 6 independent streams of depth 2
            floatx4 r_a = __builtin_amdgcn_mfma_f32_16x16x32_f16(a0, Bh[0][0], zero4, 0, 0, 0);
            floatx4 r_b = __builtin_amdgcn_mfma_f32_16x16x32_f16(a2, Bh[0][2], crin,  0, 0, 0);
            floatx4 z_a = __builtin_amdgcn_mfma_f32_16x16x32_f16(a0, Bh[1][0], zero4, 0, 0, 0);
            floatx4 z_b = __builtin_amdgcn_mfma_f32_16x16x32_f16(a2, Bh[1][2], zero4, 0, 0, 0);
            floatx4 n_a = __builtin_amdgcn_mfma_f32_16x16x32_f16(a0, Bh[2][0], cbhn,  0, 0, 0);
            floatx4 n_b = __builtin_amdgcn_mfma_f32_16x16x32_f16(a2, Bh[2][2], zero4, 0, 0, 0);
            r_a = __builtin_amdgcn_mfma_f32_16x16x32_f16(a1, Bh[0][1], r_a, 0, 0, 0);
            r_b = __builtin_amdgcn_mfma_f32_16x16x32_f16(a3, Bh[0][3], r_b, 0, 0, 0);
            z_a = __builtin_amdgcn_mfma_f32_16x16x32_f16(a1, Bh[1][1], z_a, 0, 0, 0);
            z_b = __builtin_amdgcn_mfma_f32_16x16x32_f16(a3, Bh[1][3], z_b, 0, 0, 0);
            n_a = __builtin_amdgcn_mfma_f32_16x16x32_f16(a1, Bh[2][1], n_a, 0, 0, 0);
            n_b = __builtin_amdgcn_mfma_f32_16x16x32_f16(a3, Bh[2][3], n_b, 0, 0, 0);

            // all terms in the exp2 domain (scaled by -log2e / -2log2e)
            const float urp = r_a[0] + r_b[0];              // incl. gx_r (C-in)
            const float uzp = (z_a[0] + z_b[0]) + gxz[s];   // off-spine
            const float hnp = n_a[0] + n_b[0];              // incl. bhn (C-in)
            const float xnp = gxn[s];

            // gate math, 3 exp + 2 rcp:
            // r = 1/(1+2^urp); ap = -2log2e*(xn + r*hn); e_t = 2^(-|ap|)
            // h' = [hm*(1+e_t) - copysign(e_z*(1-e_t), ap)] / [(1+e_t)*(1+e_z)]
            const float e_r = fexp2(urp);                        // inf-safe: rcp(inf)=0
            const float rg  = __builtin_amdgcn_rcpf(1.f + e_r);
            const float ap  = fmaf(rg, hnp, xnp);
            const float e_t = fexp2_nabs(ap);                    // 2^(-|ap|), (0,1]
            const float e_z = fexp2(fminf(uzp, 43.28f));         // <= 2^43.28 = e^30, finite
            const float opt = 1.f + e_t;
            const float num = fmaf(hm, opt, -copysignf(e_z * (1.f - e_t), ap));
            const float hnew = num * __builtin_amdgcn_rcpf(opt * (1.f + e_z));

            hm = mn * hnew;                                      // write LDS ASAP
            if (quad == 0) bufn[j] = (_Float16)hm;               // masked h for next step
            o[s & 3] = (quad == (s >> 2)) ? hnew : o[s & 3];     // quad-striped output regs
            if (s == 15) hr = hnew;                              // only last step matters
            BAR();
        }
    }

    // final flush: chunk 31 from registers
    {
        const int tbp = 31 * 16;
#pragma unroll
        for (int i = 0; i < 4; ++i)
            out[((size_t)(tbp + quad * 4 + i) * N_ENVS + b) * HID + j] = o[i];
    }
    if (quad == 0)
        out[(size_t)T_STEPS * N_ENVS * HID + (size_t)b * HID + j] = hr;
}

extern "C" void kernel_launch(void* const* d_in, const int* in_sizes, int n_in,
                              void* d_out, int out_size, void* d_ws, size_t ws_size,
                              hipStream_t stream) {
    const float* x   = (const float*)d_in[0];
    const float* h0  = (const float*)d_in[1];
    const float* mk  = (const float*)d_in[2];
    const float* wih = (const float*)d_in[3];
    const float* whh = (const float*)d_in[4];
    const float* bih = (const float*)d_in[5];
    const float* bhh = (const float*)d_in[6];
    float* out = (float*)d_out;

    hipLaunchKernelGGL(gru_r8, dim3(N_ENVS), dim3(NTHREADS), 0, stream,
                       x, h0, mk, wih, whh, bih, bhh, out);
}

// Round 4
// 273.958 us; speedup vs baseline: 1.0773x; 1.0773x over previous
//
#include <hip/hip_runtime.h>
#include <math.h>

#define T_STEPS  512
#define N_ENVS   256
#define STATE    64
#define HID      128
#define NTHREADS 512   // 8 waves
#define XPAD     72    // xh row stride in f16 (64 + 8 pad: breaks 16-way bank conflict)

typedef _Float16 half8   __attribute__((ext_vector_type(8)));
typedef _Float16 half4_t __attribute__((ext_vector_type(4)));
typedef float    floatx4 __attribute__((ext_vector_type(4)));

// Raw workgroup barrier: LDS visibility only (lgkmcnt), NO vmcnt/expcnt drain.
// __syncthreads() would drain vmcnt (HBM out-stores + x prefetch) at every
// step barrier; neither feeds LDS state.
#define BAR() asm volatile("s_waitcnt lgkmcnt(0)\n\ts_barrier" ::: "memory")

// v_exp_f32 is natively 2^x. Weights are pre-scaled into the exp2 domain.
__device__ __forceinline__ float fexp2(float v) {
    float r;
    asm("v_exp_f32 %0, %1" : "=v"(r) : "v"(v));
    return r;
}
// 2^(-|v|) with free source modifiers (no explicit neg/abs VALU op).
__device__ __forceinline__ float fexp2_nabs(float v) {
    float r;
    asm("v_exp_f32 %0, -|%1|" : "=v"(r) : "v"(v));
    return r;
}

// One block per env, 8 waves. Wave w owns gate rows j=16w+c for r (row j),
// z (row 128+j), n (row 256+j); lane c owns hidden unit j, quads redundant.
//
// R10 = R7 skeleton verbatim (proven passing at 223.7 us) + exactly three
// R8-proven micro-deltas:
//  - bhn folded into n-chain MFMA C-in (one dependent add off the spine)
//  - e_t via v_exp_f32 -|x| source modifier (one VALU op off the spine)
//  - hr updated only at s==15 (dead per-step move removed)
// R9's MFMA reorder + tail re-association caused an unexplained correctness
// failure and are quarantined (see session journal).
__global__ __launch_bounds__(NTHREADS, 2) void gru_r10(
    const float* __restrict__ x,      // (T*N, STATE)
    const float* __restrict__ h0,     // (N, HID)
    const float* __restrict__ masks,  // (T*N, 1) in {0,1}
    const float* __restrict__ wih,    // (3H, STATE)
    const float* __restrict__ whh,    // (3H, HID)
    const float* __restrict__ bih,    // (3H)
    const float* __restrict__ bhh,    // (3H)
    float* __restrict__ out)          // ys (T*N,H) then h_final (N,H)
{
    const int b    = blockIdx.x;
    const int tid  = threadIdx.x;
    const int w    = tid >> 6;
    const int lane = tid & 63;
    const int c    = lane & 15;
    const int quad = lane >> 4;
    const int j    = 16 * w + c;            // owned hidden unit (0..127)

    __shared__ __align__(16) _Float16 buf[2][HID];        // masked h f16, step parity
    __shared__ __align__(16) _Float16 xh[2][16][XPAD];    // x f16 per chunk (padded rows)
    __shared__ __align__(16) float    gxp[16][HID][4];    // gx+bias (exp2-scaled): [step][unit][{r,z,n,pad}] f32

    const float SRZ = -1.44269504088896341f;   // -log2(e)
    const float SN  = -2.88539008177792681f;   // -2*log2(e)
    const float scl[3] = { SRZ, SRZ, SN };

    // ---- persistent W_hh B-fragments (K=128 -> 4 chunks), exp2-pre-scaled ----
    const int rowb[3] = { j, HID + j, 2 * HID + j };
    half8 Bh[3][4];
#pragma unroll
    for (int ti = 0; ti < 3; ++ti) {
        const int g = rowb[ti];
        const float sc = scl[ti];
#pragma unroll
        for (int kt = 0; kt < 4; ++kt) {
            const float* src = whh + (size_t)g * HID + kt * 32 + quad * 8;
            const float4 p0 = *(const float4*)(src);
            const float4 p1 = *(const float4*)(src + 4);
            half8 hb;
            hb[0] = (_Float16)(sc * p0.x); hb[1] = (_Float16)(sc * p0.y);
            hb[2] = (_Float16)(sc * p0.z); hb[3] = (_Float16)(sc * p0.w);
            hb[4] = (_Float16)(sc * p1.x); hb[5] = (_Float16)(sc * p1.y);
            hb[6] = (_Float16)(sc * p1.z); hb[7] = (_Float16)(sc * p1.w);
            Bh[ti][kt] = hb;
        }
    }
    // ---- persistent W_ih B-fragments (K=64 -> 2 chunks), exp2-pre-scaled ----
    half8 Bx[3][2];
#pragma unroll
    for (int ti = 0; ti < 3; ++ti) {
        const int g = rowb[ti];
        const float sc = scl[ti];
#pragma unroll
        for (int kt = 0; kt < 2; ++kt) {
            const float* src = wih + (size_t)g * STATE + kt * 32 + quad * 8;
            const float4 p0 = *(const float4*)(src);
            const float4 p1 = *(const float4*)(src + 4);
            half8 hb;
            hb[0] = (_Float16)(sc * p0.x); hb[1] = (_Float16)(sc * p0.y);
            hb[2] = (_Float16)(sc * p0.z); hb[3] = (_Float16)(sc * p0.w);
            hb[4] = (_Float16)(sc * p1.x); hb[5] = (_Float16)(sc * p1.y);
            hb[6] = (_Float16)(sc * p1.z); hb[7] = (_Float16)(sc * p1.w);
            Bx[ti][kt] = hb;
        }
    }

    // scaled biases (exp2 domain)
    const float br  = SRZ * (bih[j] + bhh[j]);
    const float bz  = SRZ * (bih[HID + j] + bhh[HID + j]);
    const float bxn = SN  * bih[2 * HID + j];
    const float bhn = SN  * bhh[2 * HID + j];

    const floatx4 zero4 = {0.f, 0.f, 0.f, 0.f};
    floatx4 cbhn = zero4; cbhn[0] = bhn;   // loop-invariant C-in for n chain

    // ---- state / staging init ----
    float hr = h0[(size_t)b * HID + j];
    float hm = masks[b] * hr;
    if (quad == 0) buf[0][j] = (_Float16)hm;

    float4 xp = {0.f, 0.f, 0.f, 0.f};
    if (tid < 256) {   // xh[0] = x steps 0..15 ; xp = x steps 16..31
        const int k = tid >> 4, cc = (tid & 15) * 4;
        const float4 xv = *(const float4*)(x + ((size_t)k * N_ENVS + b) * STATE + cc);
        half4_t hx = {(_Float16)xv.x, (_Float16)xv.y, (_Float16)xv.z, (_Float16)xv.w};
        *(half4_t*)&xh[0][k][cc] = hx;
        xp = *(const float4*)(x + ((size_t)(16 + k) * N_ENVS + b) * STATE + cc);
    }
    // mask windows: lane l holds masks[tb+1+l] for current chunk (l = lane&15)
    float mwin     = masks[(size_t)(1  + (lane & 15)) * N_ENVS + b];
    float mwin_nxt = masks[(size_t)(17 + (lane & 15)) * N_ENVS + b];

    float o[4] = {0.f, 0.f, 0.f, 0.f};   // output regs: step s=quad*4+i -> o[i]

    BAR();   // xh[0] + buf[0] visible

    for (int tc = 0; tc < 32; ++tc) {
        // ======== chunk boundary (once per 16 steps) ========
        if (tc > 0) {   // store previous chunk's outputs straight from registers
            const int tbp = (tc - 1) * 16;
#pragma unroll
            for (int i = 0; i < 4; ++i)
                out[((size_t)(tbp + quad * 4 + i) * N_ENVS + b) * HID + j] = o[i];
            // roll mask window
            mwin = mwin_nxt;
            const int stm = (tc + 1) * 16 + 1 + (lane & 15);
            mwin_nxt = masks[(size_t)(stm < T_STEPS ? stm : T_STEPS - 1) * N_ENVS + b];
        }
        if (tid < 256) {   // xp (steps (tc+1)*16..+15) -> xh for next chunk
            const int k = tid >> 4, cc = (tid & 15) * 4;
            half4_t hx = {(_Float16)xp.x, (_Float16)xp.y, (_Float16)xp.z, (_Float16)xp.w};
            *(half4_t*)&xh[(tc + 1) & 1][k][cc] = hx;
            const int st = (tc + 2) * 16 + k;
            if (st < T_STEPS)
                xp = *(const float4*)(x + ((size_t)st * N_ENVS + b) * STATE + cc);
        }

        // batched x-projection GEMM for this chunk: A row m=c is x[step tb+c][*]
        {
            const _Float16* xr = &xh[tc & 1][c][0];
            half8 ax0 = *(const half8*)&xr[quad * 8];
            half8 ax1 = *(const half8*)&xr[32 + quad * 8];
            floatx4 g0 = __builtin_amdgcn_mfma_f32_16x16x32_f16(ax0, Bx[0][0], zero4, 0, 0, 0);
            floatx4 g1 = __builtin_amdgcn_mfma_f32_16x16x32_f16(ax0, Bx[1][0], zero4, 0, 0, 0);
            floatx4 g2 = __builtin_amdgcn_mfma_f32_16x16x32_f16(ax0, Bx[2][0], zero4, 0, 0, 0);
            g0 = __builtin_amdgcn_mfma_f32_16x16x32_f16(ax1, Bx[0][1], g0, 0, 0, 0);
            g1 = __builtin_amdgcn_mfma_f32_16x16x32_f16(ax1, Bx[1][1], g1, 0, 0, 0);
            g2 = __builtin_amdgcn_mfma_f32_16x16x32_f16(ax1, Bx[2][1], g2, 0, 0, 0);
            // D[step=quad*4+i][col=c] -> f32 {r,z,n,pad} with scaled biases folded
#pragma unroll
            for (int i = 0; i < 4; ++i) {
                floatx4 p;
                p[0] = g0[i] + br;
                p[1] = g1[i] + bz;
                p[2] = g2[i] + bxn;
                p[3] = 0.f;
                *(floatx4*)&gxp[quad * 4 + i][j][0] = p;
            }
        }
        BAR();

        // ======== 16 recurrence steps, one barrier each ========
#pragma unroll
        for (int s = 0; s < 16; ++s) {
            const int t = tc * 16 + s;
            (void)t;
            const _Float16* bufc = buf[s & 1];
            _Float16* bufn = (_Float16*)buf[(s + 1) & 1];

            // A fragments: broadcast masked h (4 K-chunks of 32)
            half8 a0 = *(const half8*)(bufc + 0 * 32 + quad * 8);
            half8 a1 = *(const half8*)(bufc + 1 * 32 + quad * 8);
            half8 a2 = *(const half8*)(bufc + 2 * 32 + quad * 8);
            half8 a3 = *(const half8*)(bufc + 3 * 32 + quad * 8);
            // x-gate terms: one b128 per lane (broadcast across quads), f32
            const floatx4 gxh = *(const floatx4*)&gxp[s][j][0];
            // masks[t+1], wave-uniform (window register always in-bounds)
            const float mn = __int_as_float(__builtin_amdgcn_readlane(__float_as_int(mwin), s));

            // 12 MFMAs, 6 independent streams of depth 2 (R7 order)
            floatx4 r_a = __builtin_amdgcn_mfma_f32_16x16x32_f16(a0, Bh[0][0], zero4, 0, 0, 0);
            floatx4 r_b = __builtin_amdgcn_mfma_f32_16x16x32_f16(a2, Bh[0][2], zero4, 0, 0, 0);
            floatx4 z_a = __builtin_amdgcn_mfma_f32_16x16x32_f16(a0, Bh[1][0], zero4, 0, 0, 0);
            floatx4 z_b = __builtin_amdgcn_mfma_f32_16x16x32_f16(a2, Bh[1][2], zero4, 0, 0, 0);
            floatx4 n_a = __builtin_amdgcn_mfma_f32_16x16x32_f16(a0, Bh[2][0], cbhn,  0, 0, 0);
            floatx4 n_b = __builtin_amdgcn_mfma_f32_16x16x32_f16(a2, Bh[2][2], zero4, 0, 0, 0);
            r_a = __builtin_amdgcn_mfma_f32_16x16x32_f16(a1, Bh[0][1], r_a, 0, 0, 0);
            r_b = __builtin_amdgcn_mfma_f32_16x16x32_f16(a3, Bh[0][3], r_b, 0, 0, 0);
            z_a = __builtin_amdgcn_mfma_f32_16x16x32_f16(a1, Bh[1][1], z_a, 0, 0, 0);
            z_b = __builtin_amdgcn_mfma_f32_16x16x32_f16(a3, Bh[1][3], z_b, 0, 0, 0);
            n_a = __builtin_amdgcn_mfma_f32_16x16x32_f16(a1, Bh[2][1], n_a, 0, 0, 0);
            n_b = __builtin_amdgcn_mfma_f32_16x16x32_f16(a3, Bh[2][3], n_b, 0, 0, 0);

            // all terms in the exp2 domain (scaled by -log2e / -2log2e)
            const float urp = (r_a[0] + r_b[0]) + gxh[0];
            const float uzp = (z_a[0] + z_b[0]) + gxh[1];
            const float hnp = n_a[0] + n_b[0];              // incl. bhn (C-in)
            const float xnp = gxh[2];

            // gate math, 3 exp + 2 rcp:
            // r = 1/(1+2^urp); ap = -2log2e*(xn + r*hn); e_t = 2^(-|ap|)
            // h' = [hm*(1+e_t) - copysign(e_z*(1-e_t), ap)] / [(1+e_t)*(1+e_z)]
            const float e_r = fexp2(urp);                        // inf-safe: rcp(inf)=0
            const float rg  = __builtin_amdgcn_rcpf(1.f + e_r);
            const float ap  = fmaf(rg, hnp, xnp);
            const float e_t = fexp2_nabs(ap);                    // 2^(-|ap|), (0,1]
            const float e_z = fexp2(fminf(uzp, 43.28f));         // <= 2^43.28 = e^30, finite
            const float opt = 1.f + e_t;
            const float num = fmaf(hm, opt, -copysignf(e_z * (1.f - e_t), ap));
            const float hnew = num * __builtin_amdgcn_rcpf(opt * (1.f + e_z));

            hm = mn * hnew;                                      // write LDS ASAP
            if (quad == 0) bufn[j] = (_Float16)hm;               // masked h for next step
            o[s & 3] = (quad == (s >> 2)) ? hnew : o[s & 3];     // quad-striped output regs
            if (s == 15) hr = hnew;                              // only last step matters
            BAR();
        }
    }

    // final flush: chunk 31 from registers
    {
        const int tbp = 31 * 16;
#pragma unroll
        for (int i = 0; i < 4; ++i)
            out[((size_t)(tbp + quad * 4 + i) * N_ENVS + b) * HID + j] = o[i];
    }
    if (quad == 0)
        out[(size_t)T_STEPS * N_ENVS * HID + (size_t)b * HID + j] = hr;
}

extern "C" void kernel_launch(void* const* d_in, const int* in_sizes, int n_in,
                              void* d_out, int out_size, void* d_ws, size_t ws_size,
                              hipStream_t stream) {
    const float* x   = (const float*)d_in[0];
    const float* h0  = (const float*)d_in[1];
    const float* mk  = (const float*)d_in[2];
    const float* wih = (const float*)d_in[3];
    const float* whh = (const float*)d_in[4];
    const float* bih = (const float*)d_in[5];
    const float* bhh = (const float*)d_in[6];
    float* out = (float*)d_out;

    hipLaunchKernelGGL(gru_r10, dim3(N_ENVS), dim3(NTHREADS), 0, stream,
                       x, h0, mk, wih, whh, bih, bhh, out);
}